// Round 1
// baseline (69.375 us; speedup 1.0000x reference)
//
#include <hip/hip_runtime.h>
#include <hip/hip_bf16.h>

// g(t) = sum_k Gamma_k * exp(-gamma_k t) * cos(omega_k t),  t in [0,10)
// Strategy: build a 65536-cell uniform table of g once per launch (cheap:
// 4.2M terms), then evaluate 2M outputs via piecewise-linear interpolation
// (memory-bound). Interp error ~1e-6 << 0.127 threshold.

#define TBL 65536            // cells; TBL+1 table points
#define TMAX 10.0f
#define K_PARAMS 64

__device__ float g_table[TBL + 1];

__global__ __launch_bounds__(256)
void build_table_kernel(const float* __restrict__ params) {
    int i = blockIdx.x * blockDim.x + threadIdx.x;
    if (i > TBL) return;
    const float t = (float)i * (TMAX / (float)TBL);
    float acc = 0.0f;
    #pragma unroll 8
    for (int k = 0; k < K_PARAMS; ++k) {
        // params uniform across lanes -> scalar loads via constant cache
        const float G  = params[k * 3 + 0];
        const float om = params[k * 3 + 1];
        const float ga = params[k * 3 + 2];
        const float e  = __expf(-ga * t);
        const float c  = __cosf(om * t);
        acc = fmaf(G * e, c, acc);
    }
    g_table[i] = acc;
}

__global__ __launch_bounds__(256)
void eval_kernel(const float* __restrict__ t, float* __restrict__ out, int T) {
    const float scale = (float)TBL / TMAX;
    const int base = (blockIdx.x * blockDim.x + threadIdx.x) * 4;
    if (base + 3 < T) {
        const float4 tv = *reinterpret_cast<const float4*>(t + base);
        float tj[4] = {tv.x, tv.y, tv.z, tv.w};
        float r[4];
        #pragma unroll
        for (int j = 0; j < 4; ++j) {
            float x = tj[j] * scale;
            int   i = (int)x;
            i = min(i, TBL - 1);
            float f = x - (float)i;
            float a = g_table[i];
            float b = g_table[i + 1];
            r[j] = fmaf(f, b - a, a);
        }
        *reinterpret_cast<float4*>(out + base) =
            make_float4(r[0], r[1], r[2], r[3]);
    } else {
        // tail (not hit for T = 2^21, kept for generality)
        for (int j = 0; j < 4; ++j) {
            int idx = base + j;
            if (idx < T) {
                float x = t[idx] * scale;
                int   i = (int)x;
                i = min(i, TBL - 1);
                float f = x - (float)i;
                float a = g_table[i];
                float b = g_table[i + 1];
                out[idx] = fmaf(f, b - a, a);
            }
        }
    }
}

extern "C" void kernel_launch(void* const* d_in, const int* in_sizes, int n_in,
                              void* d_out, int out_size, void* d_ws, size_t ws_size,
                              hipStream_t stream) {
    const float* params = (const float*)d_in[0];   // (64,3) row-major
    const float* tgrid  = (const float*)d_in[1];   // (T,)
    float* out = (float*)d_out;
    const int T = in_sizes[1];

    // 1) build table: TBL+1 points
    {
        const int threads = 256;
        const int blocks  = (TBL + 1 + threads - 1) / threads;
        build_table_kernel<<<blocks, threads, 0, stream>>>(params);
    }
    // 2) evaluate by linear interpolation, 4 elements/thread
    {
        const int threads = 256;
        const int elems_per_block = threads * 4;
        const int blocks = (T + elems_per_block - 1) / elems_per_block;
        eval_kernel<<<blocks, threads, 0, stream>>>(tgrid, out, T);
    }
}

// Round 2
// 69.367 us; speedup vs baseline: 1.0001x; 1.0001x over previous
//
#include <hip/hip_runtime.h>
#include <hip/hip_bf16.h>

// g(t) = sum_k Gamma_k * exp(-gamma_k t) * cos(omega_k t)
// Single fused kernel exploiting sorted time_grid:
//   each block owns 4096 consecutive t's (a tiny t-interval), builds a
//   257-point piecewise-linear table for that interval in LDS (adaptive
//   resolution, h ~ span/256 ~ 8e-5 -> interp error ~1e-6), then
//   interpolates 16 elems/thread with coalesced float4 loads/stores.

#define THREADS 256
#define VEC_PER_THREAD 4                 // 4 x float4 = 16 elems/thread
#define ELEMS (THREADS * VEC_PER_THREAD * 4)   // 4096 elems per block
#define PTS 257                          // table points per block
#define KPAR 64

__global__ __launch_bounds__(THREADS)
void propag_fused_kernel(const float* __restrict__ params,
                         const float* __restrict__ t,
                         float* __restrict__ out, int T) {
    __shared__ float tbl[PTS];

    const int base = blockIdx.x * ELEMS;
    const int nE   = min(ELEMS, T - base);

    // sorted input: block min/max are first/last elements (broadcast loads)
    const float tmin = t[base];
    const float tmax = t[base + nE - 1];
    const float span = fmaxf(tmax - tmin, 1e-7f);
    const float h     = span * (1.0f / (PTS - 1));
    const float inv_h = (float)(PTS - 1) / span;

    // ---- build per-block table: thread i -> point i (thread 0 also 256) ----
    for (int p = threadIdx.x; p < PTS; p += THREADS) {
        const float tp = tmin + h * (float)p;
        float acc = 0.0f;
        #pragma unroll 8
        for (int k = 0; k < KPAR; ++k) {
            // uniform across lanes -> scalar loads through constant cache
            const float G  = params[k * 3 + 0];
            const float om = params[k * 3 + 1];
            const float ga = params[k * 3 + 2];
            acc = fmaf(G * __expf(-ga * tp), __cosf(om * tp), acc);
        }
        tbl[p] = acc;
    }
    __syncthreads();

    // ---- interpolate: coalesced float4, lanes stride 16B ----
    #pragma unroll
    for (int j = 0; j < VEC_PER_THREAD; ++j) {
        const int idx = base + (j * THREADS + threadIdx.x) * 4;
        if (idx + 3 < T) {
            const float4 tv = *reinterpret_cast<const float4*>(t + idx);
            float tj[4] = {tv.x, tv.y, tv.z, tv.w};
            float r[4];
            #pragma unroll
            for (int q = 0; q < 4; ++q) {
                float x = (tj[q] - tmin) * inv_h;
                int   i = (int)x;
                i = max(0, min(i, PTS - 2));
                float f = x - (float)i;
                float a = tbl[i];
                float b = tbl[i + 1];
                r[q] = fmaf(f, b - a, a);
            }
            *reinterpret_cast<float4*>(out + idx) =
                make_float4(r[0], r[1], r[2], r[3]);
        } else {
            for (int q = 0; q < 4; ++q) {
                const int id2 = idx + q;
                if (id2 < T) {
                    float x = (t[id2] - tmin) * inv_h;
                    int   i = (int)x;
                    i = max(0, min(i, PTS - 2));
                    float f = x - (float)i;
                    out[id2] = fmaf(f, tbl[i + 1] - tbl[i], tbl[i]);
                }
            }
        }
    }
}

extern "C" void kernel_launch(void* const* d_in, const int* in_sizes, int n_in,
                              void* d_out, int out_size, void* d_ws, size_t ws_size,
                              hipStream_t stream) {
    const float* params = (const float*)d_in[0];   // (64,3) row-major
    const float* tgrid  = (const float*)d_in[1];   // (T,) sorted
    float* out = (float*)d_out;
    const int T = in_sizes[1];

    const int blocks = (T + ELEMS - 1) / ELEMS;    // 512 for T = 2^21
    propag_fused_kernel<<<blocks, THREADS, 0, stream>>>(params, tgrid, out, T);
}